// Round 5
// baseline (416.266 us; speedup 1.0000x reference)
//
#include <hip/hip_runtime.h>
#include <math.h>

// ComplexEMA single-kernel implementation.
//   y[b,d,t] = Re(sum_n gam_dn * h_dn[t]) + omega_d * x[b,d,t],
//   h[t] = q*h[t-1] + p*x[t].  Substitution u = h/p (fold p into gam and
//   final-state write).  All complex state kept in CONJUGATE form
//   (qv = -qi), so every operation is a standard complex mul/add.
//
// Parallel structure: one row (b,d) = 2 waves; each wave = 32 chunks of 64
// steps x 2 mode-halves (lane = 2*chunkLocal + half, 8 modes per lane).
//   1) stage full row x -> LDS (coalesced global, transposed, pad-33: no
//      bank conflicts), read by both recurrence passes (x hits HBM once).
//   2) pass A: local recurrence from zero -> chunk end-states (registers).
//   3) Kogge-Stone scan over chunks with __shfl_up on affine maps (A,B),
//      A = q^64; one LDS+barrier exchange between the row's two waves.
//      Replaces the old pass2 kernel and the 32 MB F workspace round-trip.
//   4) pass C: recurrence from correct chunk inits; y = own-half acc +
//      __shfl_xor(acc,1) partner + omega*x; both lanes store (full-rate,
//      plain stores -- R4 showed nontemporal stores cause 2.3x write amp).

constexpr int kD = 2048, kN = 16, kB = 2, kL = 4096;
constexpr int kRows = kB * kD;        // 4096
constexpr float kSCALE = 0.25f;       // sqrt(1/N)
constexpr int kXS = 33;               // LDS dword stride per step row (32 + 1 pad)

__global__ __launch_bounds__(256, 4) void ema_kernel(
    const float* __restrict__ x, const float* __restrict__ alpha,
    const float* __restrict__ delta, const float* __restrict__ theta,
    const float* __restrict__ gamma, const float* __restrict__ omega,
    float* __restrict__ y, float* __restrict__ hout) {

  // LDS: 4 waves * (x tile 64*33 floats + coeffs) + per-row scan boundary.
  __shared__ float xs[4][64 * kXS];     // [wave][j*33 + cL]
  __shared__ float coeff[4][88];        // [0)qr [16)qv [32)gr [48)gv [64)p [80]om
  __shared__ float btot[2][32];         // per row: wave0 inclusive total (r,v)*16

  const int tid = threadIdx.x;
  const int wave = tid >> 6, lane = tid & 63;
  const int rowL = wave >> 1, w = wave & 1;       // row-in-block, wave-in-row
  const int row = blockIdx.x * 2 + rowL;
  const int d = row & (kD - 1);
  const int cL = lane >> 1, half = lane & 1;      // chunkLocal 0..31, mode-half

  // ---- coefficients (lanes 0..15 of each wave compute its row's 16 modes) ----
  if (lane < kN) {
    int n = lane, i = d * kN + n;
    float p  = 1.f / (1.f + expf(-alpha[i]));
    float dd = 1.f / (1.f + expf(-delta[i]));
    float th = 1.f / (1.f + expf(-theta[d]));
    float phi = (float)(n + 1) * th * 0.39269908169872414f;  // 2*pi/16
    float r = 1.f - p * dd;
    float s, c;
    sincosf(phi, &s, &c);
    coeff[wave][n]      = r * c;                     // qr
    coeff[wave][16 + n] = -r * s;                    // qv = -qi (conjugate form)
    coeff[wave][32 + n] = p * kSCALE * gamma[2 * i];     // gr
    coeff[wave][48 + n] = p * kSCALE * gamma[2 * i + 1]; // gv
    coeff[wave][64 + n] = p;
    if (n == 0) coeff[wave][80] = omega[d];
  }

  // ---- stage this wave's half-row (2048 floats) coalesced -> LDS transposed ----
  {
    const float4* xp = (const float4*)(x + (size_t)row * kL + w * 2048);
#pragma unroll
    for (int m = 0; m < 8; m++) {
      float4 t = xp[m * 64 + lane];                // 1KB coalesced per instr
      int cc = 4 * m + (lane >> 4);                // chunkLocal this piece lands in
      int jb = 4 * (lane & 15);                    // step base
      xs[wave][(jb + 0) * kXS + cc] = t.x;
      xs[wave][(jb + 1) * kXS + cc] = t.y;
      xs[wave][(jb + 2) * kXS + cc] = t.z;
      xs[wave][(jb + 3) * kXS + cc] = t.w;
    }
  }
  __syncthreads();

  // ---- per-lane coefficients (8 modes) ----
  float qr[8], qv[8];
#pragma unroll
  for (int m = 0; m < 8; m++) {
    qr[m] = coeff[wave][8 * half + m];
    qv[m] = coeff[wave][16 + 8 * half + m];
  }

  // ---- pass A: local recurrence from zero (end state -> ur/uv) ----
  float ur[8], uv[8];
#pragma unroll
  for (int m = 0; m < 8; m++) { ur[m] = 0.f; uv[m] = 0.f; }
#pragma unroll 1
  for (int j0 = 0; j0 < 64; j0 += 16) {
#pragma unroll
    for (int jj = 0; jj < 16; jj++) {
      float xv = xs[wave][(j0 + jj) * kXS + cL];
#pragma unroll
      for (int m = 0; m < 8; m++) {
        float nr = fmaf(qr[m], ur[m], fmaf(-qv[m], uv[m], xv));
        float nv = fmaf(qr[m], uv[m], qv[m] * ur[m]);
        ur[m] = nr; uv[m] = nv;
      }
    }
  }

  // ---- scan over chunks: affine maps (A, B), A = q^64, B = local end state ----
  float Ar[8], Av[8];
#pragma unroll
  for (int m = 0; m < 8; m++) { Ar[m] = qr[m]; Av[m] = qv[m]; }
#pragma unroll
  for (int k = 0; k < 6; k++) {                    // q^64 by 6 squarings
#pragma unroll
    for (int m = 0; m < 8; m++) {
      float t = Ar[m] * Ar[m] - Av[m] * Av[m];
      Av[m] = 2.f * Ar[m] * Av[m];
      Ar[m] = t;
    }
  }
  // Kogge-Stone inclusive scan within wave (32 chunks, lane distance = 2*d)
#pragma unroll
  for (int dd = 1; dd <= 16; dd <<= 1) {
    bool act = (cL >= dd);
#pragma unroll
    for (int m = 0; m < 8; m++) {
      float oBr = __shfl_up(ur[m], 2 * dd, 64);
      float oBv = __shfl_up(uv[m], 2 * dd, 64);
      float oAr = __shfl_up(Ar[m], 2 * dd, 64);
      float oAv = __shfl_up(Av[m], 2 * dd, 64);
      if (act) {
        ur[m] = fmaf(Ar[m], oBr, fmaf(-Av[m], oBv, ur[m]));
        uv[m] = fmaf(Ar[m], oBv, fmaf(Av[m], oBr, uv[m]));
        float t = Ar[m] * oAr - Av[m] * oAv;
        Av[m] = fmaf(Ar[m], oAv, Av[m] * oAr);
        Ar[m] = t;
      }
    }
  }
  // cross-wave: wave0's inclusive total (chunk 31) -> wave1
  if (w == 0 && cL == 31) {
#pragma unroll
    for (int m = 0; m < 8; m++) {
      btot[rowL][(8 * half + m) * 2]     = ur[m];
      btot[rowL][(8 * half + m) * 2 + 1] = uv[m];
    }
  }
  __syncthreads();
  float tr[8], tv[8];
#pragma unroll
  for (int m = 0; m < 8; m++) { tr[m] = 0.f; tv[m] = 0.f; }
  if (w == 1) {
#pragma unroll
    for (int m = 0; m < 8; m++) {
      tr[m] = btot[rowL][(8 * half + m) * 2];
      tv[m] = btot[rowL][(8 * half + m) * 2 + 1];
    }
#pragma unroll
    for (int m = 0; m < 8; m++) {                  // compose with left-half total
      float nr = fmaf(Ar[m], tr[m], fmaf(-Av[m], tv[m], ur[m]));
      float nv = fmaf(Ar[m], tv[m], fmaf(Av[m], tr[m], uv[m]));
      ur[m] = nr; uv[m] = nv;
    }
  }
  // h_last output (row's final state = wave1 chunk31 inclusive): h = p*u,
  // true imag = -uv.  (B,D,N,2) layout, lane-half writes 16 contiguous floats.
  if (w == 1 && cL == 31) {
    float4* hp = (float4*)(hout + (size_t)row * 32 + half * 16);
#pragma unroll
    for (int k = 0; k < 4; k++) {
      int m0 = 2 * k, m1 = 2 * k + 1;
      float p0 = coeff[wave][64 + 8 * half + m0];
      float p1 = coeff[wave][64 + 8 * half + m1];
      hp[k] = make_float4(p0 * ur[m0], -p0 * uv[m0], p1 * ur[m1], -p1 * uv[m1]);
    }
  }
  // exclusive shift: state entering chunk c = inclusive[c-1]
#pragma unroll
  for (int m = 0; m < 8; m++) {
    float hr = __shfl_up(ur[m], 2, 64);
    float hv = __shfl_up(uv[m], 2, 64);
    if (cL == 0) { hr = (w == 1) ? tr[m] : 0.f; hv = (w == 1) ? tv[m] : 0.f; }
    ur[m] = hr; uv[m] = hv;
  }

  // ---- pass C: recurrence from correct inits, emit y ----
  float gr[8], gv[8];
#pragma unroll
  for (int m = 0; m < 8; m++) {
    gr[m] = coeff[wave][32 + 8 * half + m];
    gv[m] = coeff[wave][48 + 8 * half + m];
  }
  float om = coeff[wave][80];
  float* ybase = y + (size_t)row * kL + (size_t)(w * 32 + cL) * 64 + half * 8;
  float buf[8];
#pragma unroll 1
  for (int j0 = 0; j0 < 64; j0 += 16) {
#pragma unroll
    for (int jj = 0; jj < 16; jj++) {
      float xv = xs[wave][(j0 + jj) * kXS + cL];
      float acc = 0.f;
#pragma unroll
      for (int m = 0; m < 8; m++) {
        float nr = fmaf(qr[m], ur[m], fmaf(-qv[m], uv[m], xv));
        float nv = fmaf(qr[m], uv[m], qv[m] * ur[m]);
        ur[m] = nr; uv[m] = nv;
        acc = fmaf(gr[m], nr, fmaf(gv[m], nv, acc));
      }
      float ytot = acc + __shfl_xor(acc, 1, 64);   // combine mode-halves
      ytot = fmaf(om, xv, ytot);
      if ((jj & 8) == half * 8) buf[jj & 7] = ytot;  // keep own half's steps
    }
    // even lane stores steps [j0, j0+8), odd lane [j0+8, j0+16)
    float4* yp = (float4*)(ybase + j0);
    yp[0] = make_float4(buf[0], buf[1], buf[2], buf[3]);
    yp[1] = make_float4(buf[4], buf[5], buf[6], buf[7]);
  }
}

extern "C" void kernel_launch(void* const* d_in, const int* in_sizes, int n_in,
                              void* d_out, int out_size, void* d_ws, size_t ws_size,
                              hipStream_t stream) {
  const float* x     = (const float*)d_in[0];
  const float* alpha = (const float*)d_in[1];
  const float* delta = (const float*)d_in[2];
  const float* theta = (const float*)d_in[3];
  const float* gamma = (const float*)d_in[4];
  const float* omega = (const float*)d_in[5];
  float* y    = (float*)d_out;
  float* hout = y + (size_t)kB * kD * kL;          // (B,D,N,2) after y
  ema_kernel<<<kRows / 2, 256, 0, stream>>>(x, alpha, delta, theta, gamma,
                                            omega, y, hout);
}

// Round 6
// 210.298 us; speedup vs baseline: 1.9794x; 1.9794x over previous
//
#include <hip/hip_runtime.h>
#include <math.h>

// ComplexEMA fused single-kernel.
//   y[b,d,t] = Re(sum_n gam_dn * h_dn[t]) + omega_d * x[b,d,t],
//   h[t] = q*h[t-1] + p*x[t].   u = h/p (p folded into gam / final write).
// Conjugate-form state (v = -imag) -> no component swaps:
//   ur' = qr*ur - qv*uv + x ; uv' = qr*uv + qv*ur ; Re(gam*h)=gr*ur+gv*uv.
//
// One wave = one row (b,d). lane = chunk (64 chunks x 64 steps).
//   A) local 64-step recurrence from zero (x direct from global, 64B bursts)
//   B) Kogge-Stone scan over chunks via __shfl_up on affine maps (A=q^64)
//   C) rerun from correct chunk inits, y overwrites the x register buffer,
//      stored in 64B bursts.
// Wave-uniform coefficients (q, g, omega) are pinned to SGPRs via
// readfirstlane -- R5 died of VGPR spills (FETCH+WRITE 1.3GB of scratch).

constexpr int kD = 2048, kN = 16, kB = 2, kL = 4096;
constexpr int kRows = kB * kD;      // 4096 rows = 4096 waves
constexpr float kSCALE = 0.25f;     // sqrt(1/N)

static __device__ __forceinline__ float uniformf(float v) {
  // wave-uniform value -> SGPR
  return __int_as_float(__builtin_amdgcn_readfirstlane(__float_as_int(v)));
}

static __device__ __forceinline__ void load16(const float* __restrict__ p, float* v) {
  const float4* p4 = (const float4*)p;
  float4 t0 = p4[0], t1 = p4[1], t2 = p4[2], t3 = p4[3];
  v[0]=t0.x; v[1]=t0.y; v[2]=t0.z; v[3]=t0.w;
  v[4]=t1.x; v[5]=t1.y; v[6]=t1.z; v[7]=t1.w;
  v[8]=t2.x; v[9]=t2.y; v[10]=t2.z; v[11]=t2.w;
  v[12]=t3.x; v[13]=t3.y; v[14]=t3.z; v[15]=t3.w;
}

static __device__ __forceinline__ void store16(float* __restrict__ p, const float* v) {
  float4* p4 = (float4*)p;
  p4[0] = make_float4(v[0], v[1], v[2], v[3]);
  p4[1] = make_float4(v[4], v[5], v[6], v[7]);
  p4[2] = make_float4(v[8], v[9], v[10], v[11]);
  p4[3] = make_float4(v[12], v[13], v[14], v[15]);
}

// 16 recurrence steps, no output (pass A)
static __device__ __forceinline__ void steps16A(const float* xv, float* ur, float* uv,
                                                const float* qr, const float* qv) {
#pragma unroll
  for (int j = 0; j < 16; j++) {
    float xj = xv[j];
#pragma unroll
    for (int m = 0; m < 16; m++) {
      float nr = fmaf(qr[m], ur[m], fmaf(-qv[m], uv[m], xj));
      uv[m] = fmaf(qr[m], uv[m], qv[m] * ur[m]);
      ur[m] = nr;
    }
  }
}

// 16 recurrence steps + y emission, y overwrites v[] in place (pass C)
static __device__ __forceinline__ void steps16C(float* v, float* ur, float* uv,
    const float* qr, const float* qv, const float* gr, const float* gv, float om) {
#pragma unroll
  for (int j = 0; j < 16; j++) {
    float xj = v[j];
    float a[4] = {0.f, 0.f, 0.f, 0.f};
#pragma unroll
    for (int m = 0; m < 16; m++) {
      float nr = fmaf(qr[m], ur[m], fmaf(-qv[m], uv[m], xj));
      float nv = fmaf(qr[m], uv[m], qv[m] * ur[m]);
      ur[m] = nr; uv[m] = nv;
      a[m & 3] = fmaf(gr[m], nr, fmaf(gv[m], nv, a[m & 3]));
    }
    v[j] = fmaf(om, xj, (a[0] + a[1]) + (a[2] + a[3]));
  }
}

__global__ __launch_bounds__(256) void ema_kernel(
    const float* __restrict__ x, const float* __restrict__ alpha,
    const float* __restrict__ delta, const float* __restrict__ theta,
    const float* __restrict__ gamma, const float* __restrict__ omega,
    float* __restrict__ y, float* __restrict__ hout) {
  __shared__ float coeff[4][96];  // per wave/row: [0)qr [16)qv [32)gr [48)gv [64)p [80]om

  const int tid = threadIdx.x, wave = tid >> 6, lane = tid & 63;
  const int row = blockIdx.x * 4 + wave, d = row & (kD - 1);

  // ---- coefficients (lanes 0..15 of each wave -> LDS) ----
  if (lane < kN) {
    int n = lane, i = d * kN + n;
    float p  = 1.f / (1.f + expf(-alpha[i]));
    float dd = 1.f / (1.f + expf(-delta[i]));
    float th = 1.f / (1.f + expf(-theta[d]));
    float phi = (float)(n + 1) * th * 0.39269908169872414f;  // 2*pi/16
    float r = 1.f - p * dd;
    float s, c;
    sincosf(phi, &s, &c);
    coeff[wave][n]      = r * c;                         // qr
    coeff[wave][16 + n] = -r * s;                        // qv = -qi
    coeff[wave][32 + n] = p * kSCALE * gamma[2 * i];     // gr
    coeff[wave][48 + n] = p * kSCALE * gamma[2 * i + 1]; // gv
    coeff[wave][64 + n] = p;
    if (n == 0) coeff[wave][80] = omega[d];
  }
  __syncthreads();

  // ---- q into SGPRs ----
  float qr[16], qv[16];
#pragma unroll
  for (int m = 0; m < 16; m++) {
    qr[m] = uniformf(coeff[wave][m]);
    qv[m] = uniformf(coeff[wave][16 + m]);
  }

  const float* xrow = x + (size_t)row * kL + lane * 64;

  // ---- pass A: local recurrence from zero ----
  float ur[16], uv[16];
#pragma unroll
  for (int m = 0; m < 16; m++) { ur[m] = 0.f; uv[m] = 0.f; }
  float xa[16], xb[16];
  load16(xrow, xa);
  load16(xrow + 16, xb);          // prefetch
  steps16A(xa, ur, uv, qr, qv);
  load16(xrow + 32, xa);          // prefetch
  steps16A(xb, ur, uv, qr, qv);
  load16(xrow + 48, xb);          // prefetch
  steps16A(xa, ur, uv, qr, qv);
  steps16A(xb, ur, uv, qr, qv);

  // ---- scan over chunks: affine (A,B), A = q^64 ----
  float Ar[16], Av[16];
#pragma unroll
  for (int m = 0; m < 16; m++) { Ar[m] = qr[m]; Av[m] = qv[m]; }
#pragma unroll
  for (int k = 0; k < 6; k++) {   // 6 squarings -> q^64
#pragma unroll
    for (int m = 0; m < 16; m++) {
      float t = Ar[m] * Ar[m] - Av[m] * Av[m];
      Av[m] = 2.f * Ar[m] * Av[m];
      Ar[m] = t;
    }
  }
#pragma unroll
  for (int dd2 = 1; dd2 <= 32; dd2 <<= 1) {   // Kogge-Stone inclusive
#pragma unroll
    for (int m = 0; m < 16; m++) {
      float oBr = __shfl_up(ur[m], dd2, 64);
      float oBv = __shfl_up(uv[m], dd2, 64);
      float oAr = __shfl_up(Ar[m], dd2, 64);
      float oAv = __shfl_up(Av[m], dd2, 64);
      if (lane >= dd2) {
        ur[m] = fmaf(Ar[m], oBr, fmaf(-Av[m], oBv, ur[m]));
        uv[m] = fmaf(Ar[m], oBv, fmaf(Av[m], oBr, uv[m]));
        float t = Ar[m] * oAr - Av[m] * oAv;
        Av[m] = fmaf(Ar[m], oAv, Av[m] * oAr);
        Ar[m] = t;
      }
    }
  }

  // ---- h_last: lane 63 holds the row's final state. h = p*u, imag = -uv ----
  if (lane == 63) {
    float4* hp = (float4*)(hout + (size_t)row * 32);
#pragma unroll
    for (int k = 0; k < 8; k++) {
      int m0 = 2 * k, m1 = 2 * k + 1;
      float p0 = coeff[wave][64 + m0];
      float p1 = coeff[wave][64 + m1];
      hp[k] = make_float4(p0 * ur[m0], -p0 * uv[m0], p1 * ur[m1], -p1 * uv[m1]);
    }
  }

  // ---- exclusive shift: state entering my chunk = inclusive[lane-1] ----
#pragma unroll
  for (int m = 0; m < 16; m++) {
    float hr = __shfl_up(ur[m], 1, 64);
    float hv = __shfl_up(uv[m], 1, 64);
    ur[m] = (lane == 0) ? 0.f : hr;
    uv[m] = (lane == 0) ? 0.f : hv;
  }

  // ---- g, omega into SGPRs (A dead now) ----
  float gr[16], gv[16];
#pragma unroll
  for (int m = 0; m < 16; m++) {
    gr[m] = uniformf(coeff[wave][32 + m]);
    gv[m] = uniformf(coeff[wave][48 + m]);
  }
  float om = uniformf(coeff[wave][80]);

  // ---- pass C: recurrence from correct inits, emit y ----
  float* yrow = y + (size_t)row * kL + lane * 64;
  load16(xrow, xa);               // L2/L3-warm re-read
  load16(xrow + 16, xb);
  steps16C(xa, ur, uv, qr, qv, gr, gv, om);
  store16(yrow, xa);
  load16(xrow + 32, xa);
  steps16C(xb, ur, uv, qr, qv, gr, gv, om);
  store16(yrow + 16, xb);
  load16(xrow + 48, xb);
  steps16C(xa, ur, uv, qr, qv, gr, gv, om);
  store16(yrow + 32, xa);
  steps16C(xb, ur, uv, qr, qv, gr, gv, om);
  store16(yrow + 48, xb);
}

extern "C" void kernel_launch(void* const* d_in, const int* in_sizes, int n_in,
                              void* d_out, int out_size, void* d_ws, size_t ws_size,
                              hipStream_t stream) {
  const float* x     = (const float*)d_in[0];
  const float* alpha = (const float*)d_in[1];
  const float* delta = (const float*)d_in[2];
  const float* theta = (const float*)d_in[3];
  const float* gamma = (const float*)d_in[4];
  const float* omega = (const float*)d_in[5];
  float* y    = (float*)d_out;
  float* hout = y + (size_t)kB * kD * kL;   // (B,D,N,2) after y
  ema_kernel<<<kRows / 4, 256, 0, stream>>>(x, alpha, delta, theta, gamma,
                                            omega, y, hout);
}